// Round 4
// baseline (32889.481 us; speedup 1.0000x reference)
//
#include <hip/hip_runtime.h>

// Problem constants (B,S,F,L) = (512, 1024, 64, 128)
constexpr int Bn = 512;
constexpr int Sn = 1024;
constexpr int Fn = 64;
constexpr int Ln = 128;
constexpr int Gn = 4 * Ln;  // 512 gate rows (i,f,g,o)

typedef float v2f __attribute__((ext_vector_type(2)));

// ---- cross-lane helpers ----
template <int CTRL>
__device__ __forceinline__ float dpp_add(float v) {
  int s = __builtin_amdgcn_mov_dpp(__float_as_int(v), CTRL, 0xF, 0xF, true);
  return v + __int_as_float(s);
}
// 0xB1 = quad_perm(1,0,3,2) = xor1; 0x4E = quad_perm(2,3,0,1) = xor2
__device__ __forceinline__ float swz4_add(float v) {  // xor4 via ds_swizzle bitmode
  int s = __builtin_amdgcn_ds_swizzle(__float_as_int(v), 0x101F);
  return v + __int_as_float(s);
}

__device__ __forceinline__ float fsig(float v) {
  return __builtin_amdgcn_rcpf(1.0f + __expf(-v));
}
__device__ __forceinline__ float ftanh(float v) {
  return 2.0f * __builtin_amdgcn_rcpf(1.0f + __expf(-2.0f * v)) - 1.0f;
}

// Fold decoder dense layer into the decoder recurrence:
//   W_comb[t,l] = W_hh_dec[t,l] + sum_j W_ih_dec[t,j] * W_dense[j,l]
//   b_comb[t]   = b_ih_dec[t] + b_hh_dec[t] + sum_j W_ih_dec[t,j] * b_dense[j]
__global__ void combine_dec_kernel(const float* __restrict__ Wih, const float* __restrict__ Whh,
                                   const float* __restrict__ bih, const float* __restrict__ bhh,
                                   const float* __restrict__ Wd, const float* __restrict__ bd,
                                   float* __restrict__ Wc, float* __restrict__ bc) {
  const int t = blockIdx.x;   // gate row 0..511
  const int l = threadIdx.x;  // latent col 0..127
  float s = Whh[t * Ln + l];
#pragma unroll
  for (int j = 0; j < Fn; ++j) s += Wih[t * Fn + j] * Wd[j * Ln + l];
  Wc[t * Ln + l] = s;
  if (l == 0) {
    float sb = bih[t] + bhh[t];
#pragma unroll
    for (int j = 0; j < Fn; ++j) sb += Wih[t * Fn + j] * bd[j];
    bc[t] = sb;
  }
}

// Persistent RNN: 256 blocks x 512 threads, 2 batch elems per block.
// __launch_bounds__(512, 1): empirically the 2nd arg acts as min BLOCKS/CU
// (CUDA semantics) -- (1024,4) gave a 64-VGPR cap (r2), (512,2) gave 128 (r3,
// spilled 26 GB to scratch). (512,1) = 8 waves/CU = 2 waves/SIMD = 256-VGPR
// cap; the ~215 live floats fit with no spill and no AGPR copies.
// Thread t: q = t&3 (K-quarter), rA = t>>2 (latent). Owns gate rows
// {rA, rA+128, rA+256, rA+384} = (i,f,g,o) of latent rA -> after the 4-lane
// DPP quad reduce, the cell update is LOCAL (one barrier per step).
// Accumulators are v2f (elem0,elem1) to get v_pk_fma_f32 (2x fp32/inst).
__global__ __launch_bounds__(512, 1) void rae_persistent_kernel(
    const float* __restrict__ x,
    const float* __restrict__ Wih_e, const float* __restrict__ Whh_e,
    const float* __restrict__ bih_e, const float* __restrict__ bhh_e,
    const float* __restrict__ Wc, const float* __restrict__ bc,
    const float* __restrict__ Wd, const float* __restrict__ bd,
    float* __restrict__ out) {
  const int t = threadIdx.x;
  const int q = t & 3;    // K-quarter: x[16q..16q+16), h[32q..32q+32)
  const int rA = t >> 2;  // latent 0..127
  const int b0 = blockIdx.x * 2;

  __shared__ __align__(16) float hs[2][4][68];  // [buf][quarter][32 latents x 2 elems + 4 pad]
  __shared__ __align__(16) float xs[2][4][36];  // [buf][quarter][16 feats x 2 elems + 4 pad]

  // ---- encoder weights: 4 gate rows x (32 h + 16 x) = 192 fp32 regs ----
  float wh[4][32], wx[4][16], bias[4];
#pragma unroll
  for (int g = 0; g < 4; ++g) {
    const int row = g * Ln + rA;
    const float4* ph = (const float4*)(Whh_e + row * Ln + q * 32);
#pragma unroll
    for (int k = 0; k < 8; ++k) {
      float4 v = ph[k];
      wh[g][4 * k] = v.x; wh[g][4 * k + 1] = v.y; wh[g][4 * k + 2] = v.z; wh[g][4 * k + 3] = v.w;
    }
    const float4* px = (const float4*)(Wih_e + row * Fn + q * 16);
#pragma unroll
    for (int k = 0; k < 4; ++k) {
      float4 v = px[k];
      wx[g][4 * k] = v.x; wx[g][4 * k + 1] = v.y; wx[g][4 * k + 2] = v.z; wx[g][4 * k + 3] = v.w;
    }
    bias[g] = bih_e[row] + bhh_e[row];
  }

  float c = 0.0f;  // valid on lanes q<2: cell state for (latent rA, elem q)

  // x prefetch slot: t<128 -> (elem e_, feature f_)
  const int f_ = t & 63, e_ = (t >> 6) & 1;
  const float* xbase = x + (size_t)(b0 + e_) * Sn * Fn + f_;

  if (t < Ln) {
    hs[0][t >> 5][(t & 31) * 2] = 0.0f;
    hs[0][t >> 5][(t & 31) * 2 + 1] = 0.0f;
    xs[0][f_ >> 4][(f_ & 15) * 2 + e_] = xbase[0];
  }
  __syncthreads();

  // ================= encoder: 1024 steps =================
  for (int step = 0; step < Sn; ++step) {
    const int cur = step & 1, nx = cur ^ 1;
    float xv = 0.0f;
    if (t < Ln && step + 1 < Sn) xv = xbase[(size_t)(step + 1) * Fn];

    v2f a[4];
#pragma unroll
    for (int g = 0; g < 4; ++g) a[g] = (v2f){0.0f, 0.0f};

    const float4* x4 = (const float4*)&xs[cur][q][0];
#pragma unroll
    for (int k = 0; k < 8; ++k) {  // features 16q+2k, +2k+1, both elems
      float4 v = x4[k];
      v2f v01 = (v2f){v.x, v.y}, v23 = (v2f){v.z, v.w};
#pragma unroll
      for (int g = 0; g < 4; ++g) {
        a[g] += (v2f){wx[g][2 * k], wx[g][2 * k]} * v01;
        a[g] += (v2f){wx[g][2 * k + 1], wx[g][2 * k + 1]} * v23;
      }
    }
    const float4* h4 = (const float4*)&hs[cur][q][0];
#pragma unroll
    for (int k = 0; k < 16; ++k) {  // latents 32q+2k, +2k+1, both elems
      float4 v = h4[k];
      v2f v01 = (v2f){v.x, v.y}, v23 = (v2f){v.z, v.w};
#pragma unroll
      for (int g = 0; g < 4; ++g) {
        a[g] += (v2f){wh[g][2 * k], wh[g][2 * k]} * v01;
        a[g] += (v2f){wh[g][2 * k + 1], wh[g][2 * k + 1]} * v23;
      }
    }
    // quad all-reduce per component (DPP xor1, xor2)
    float s[4][2];
#pragma unroll
    for (int g = 0; g < 4; ++g) {
      s[g][0] = dpp_add<0x4E>(dpp_add<0xB1>(a[g].x));
      s[g][1] = dpp_add<0x4E>(dpp_add<0xB1>(a[g].y));
    }
    if (q < 2) {  // lane q handles elem q: local cell update
      float gi = fsig(s[0][q] + bias[0]);
      float gf = fsig(s[1][q] + bias[1]);
      float gg = ftanh(s[2][q] + bias[2]);
      float go = fsig(s[3][q] + bias[3]);
      c = gf * c + gi * gg;
      hs[nx][rA >> 5][(rA & 31) * 2 + q] = go * ftanh(c);
    }
    if (t < Ln && step + 1 < Sn) xs[nx][f_ >> 4][(f_ & 15) * 2 + e_] = xv;
    __syncthreads();
  }

  // ================= decoder: 1024 steps =================
#pragma unroll
  for (int g = 0; g < 4; ++g) {  // reload wh with folded W_comb
    const int row = g * Ln + rA;
    const float4* pc = (const float4*)(Wc + row * Ln + q * 32);
#pragma unroll
    for (int k = 0; k < 8; ++k) {
      float4 v = pc[k];
      wh[g][4 * k] = v.x; wh[g][4 * k + 1] = v.y; wh[g][4 * k + 2] = v.z; wh[g][4 * k + 3] = v.w;
    }
    bias[g] = bc[row];
  }
  // dense epilogue: 8 lanes per output feature, 16 latents each
  const int oj = t >> 3, sl = t & 7;
  float dw[16];
  {
    const float4* pd = (const float4*)(Wd + oj * Ln + sl * 16);
#pragma unroll
    for (int k = 0; k < 4; ++k) {
      float4 v = pd[k];
      dw[4 * k] = v.x; dw[4 * k + 1] = v.y; dw[4 * k + 2] = v.z; dw[4 * k + 3] = v.w;
    }
  }
  const float dbias = bd[oj];
  float* opA = out + (size_t)b0 * Sn * Fn + (size_t)(Sn - 1) * Fn + oj;
  float* opB = opA + (size_t)Sn * Fn;

  for (int step = 0; step < Sn; ++step) {
    const int cur = step & 1, nx = cur ^ 1;
    v2f a[4];
#pragma unroll
    for (int g = 0; g < 4; ++g) a[g] = (v2f){0.0f, 0.0f};

    const float4* h4 = (const float4*)&hs[cur][q][0];
#pragma unroll
    for (int k = 0; k < 16; ++k) {
      float4 v = h4[k];
      v2f v01 = (v2f){v.x, v.y}, v23 = (v2f){v.z, v.w};
#pragma unroll
      for (int g = 0; g < 4; ++g) {
        a[g] += (v2f){wh[g][2 * k], wh[g][2 * k]} * v01;
        a[g] += (v2f){wh[g][2 * k + 1], wh[g][2 * k + 1]} * v23;
      }
    }
    float s[4][2];
#pragma unroll
    for (int g = 0; g < 4; ++g) {
      s[g][0] = dpp_add<0x4E>(dpp_add<0xB1>(a[g].x));
      s[g][1] = dpp_add<0x4E>(dpp_add<0xB1>(a[g].y));
    }
    if (q < 2) {
      float gi = fsig(s[0][q] + bias[0]);
      float gf = fsig(s[1][q] + bias[1]);
      float gg = ftanh(s[2][q] + bias[2]);
      float go = fsig(s[3][q] + bias[3]);
      c = gf * c + gi * gg;
      hs[nx][rA >> 5][(rA & 31) * 2 + q] = go * ftanh(c);
    }
    __syncthreads();

    // dense epilogue on the just-written h (buffer nx): out[b, S-1-step, :]
    const float4* he = (const float4*)&hs[nx][sl >> 1][0];
    v2f d = (v2f){0.0f, 0.0f};
#pragma unroll
    for (int k = 0; k < 8; ++k) {  // latents 16*sl + 2k, +2k+1
      float4 v = he[(sl & 1) * 8 + k];
      d += (v2f){dw[2 * k], dw[2 * k]} * (v2f){v.x, v.y};
      d += (v2f){dw[2 * k + 1], dw[2 * k + 1]} * (v2f){v.z, v.w};
    }
    float d0 = swz4_add(dpp_add<0x4E>(dpp_add<0xB1>(d.x)));
    float d1 = swz4_add(dpp_add<0x4E>(dpp_add<0xB1>(d.y)));
    if (sl == 0) {
      opA[0] = d0 + dbias;
      opB[0] = d1 + dbias;
    }
    opA -= Fn;
    opB -= Fn;
  }
}

extern "C" void kernel_launch(void* const* d_in, const int* in_sizes, int n_in,
                              void* d_out, int out_size, void* d_ws, size_t ws_size,
                              hipStream_t stream) {
  const float* x     = (const float*)d_in[0];
  const float* Wih_e = (const float*)d_in[1];
  const float* Whh_e = (const float*)d_in[2];
  const float* bih_e = (const float*)d_in[3];
  const float* bhh_e = (const float*)d_in[4];
  const float* Wih_d = (const float*)d_in[5];
  const float* Whh_d = (const float*)d_in[6];
  const float* bih_d = (const float*)d_in[7];
  const float* bhh_d = (const float*)d_in[8];
  const float* Wd    = (const float*)d_in[9];
  const float* bd    = (const float*)d_in[10];
  float* out = (float*)d_out;

  float* Wc = (float*)d_ws;          // 512*128 floats
  float* bc = Wc + (size_t)Gn * Ln;  // 512 floats

  combine_dec_kernel<<<Gn, Ln, 0, stream>>>(Wih_d, Whh_d, bih_d, bhh_d, Wd, bd, Wc, bc);
  rae_persistent_kernel<<<Bn / 2, 512, 0, stream>>>(x, Wih_e, Whh_e, bih_e, bhh_e,
                                                    Wc, bc, Wd, bd, out);
}

// Round 6
// 2790.401 us; speedup vs baseline: 11.7867x; 11.7867x over previous
//
#include <hip/hip_runtime.h>

// Problem constants (B,S,F,L) = (512, 1024, 64, 128)
constexpr int Bn = 512;
constexpr int Sn = 1024;
constexpr int Fn = 64;
constexpr int Ln = 128;
constexpr int Gn = 4 * Ln;  // 512 gate rows (i,f,g,o)

typedef unsigned int u32;
typedef _Float16 h2 __attribute__((ext_vector_type(2)));

// ---- cross-lane helpers ----
template <int CTRL>
__device__ __forceinline__ float dpp_add(float v) {
  int s = __builtin_amdgcn_mov_dpp(__float_as_int(v), CTRL, 0xF, 0xF, true);
  return v + __int_as_float(s);
}
// 0xB1 = quad_perm(1,0,3,2) = xor1; 0x4E = quad_perm(2,3,0,1) = xor2

__device__ __forceinline__ float fdot2(u32 a, u32 b, float c) {
  return __builtin_amdgcn_fdot2(__builtin_bit_cast(h2, a), __builtin_bit_cast(h2, b), c, false);
}

__device__ __forceinline__ float fsig(float v) {
  return __builtin_amdgcn_rcpf(1.0f + __expf(-v));
}
__device__ __forceinline__ float ftanh(float v) {
  return 2.0f * __builtin_amdgcn_rcpf(1.0f + __expf(-2.0f * v)) - 1.0f;
}

// Pack encoder weights + dense weights to fp16 in workspace.
__global__ void pack_kernel(const float* __restrict__ Wih, const float* __restrict__ Whh,
                            const float* __restrict__ Wd,
                            _Float16* __restrict__ WhE, _Float16* __restrict__ WxE,
                            _Float16* __restrict__ WdH) {
  const int i = blockIdx.x * 256 + threadIdx.x;  // grid covers 65536
  if (i < Gn * Ln) WhE[i] = (_Float16)Whh[i];
  if (i < Gn * Fn) WxE[i] = (_Float16)Wih[i];
  if (i < Fn * Ln) WdH[i] = (_Float16)Wd[i];
}

// Fold decoder dense into the recurrence (fp32 math, fp16 result):
//   W_comb[t,l] = W_hh_dec[t,l] + sum_j W_ih_dec[t,j] * W_dense[j,l]
//   b_comb[t]   = b_ih_dec[t] + b_hh_dec[t] + sum_j W_ih_dec[t,j] * b_dense[j]
__global__ void combine_dec_kernel(const float* __restrict__ Wih, const float* __restrict__ Whh,
                                   const float* __restrict__ bih, const float* __restrict__ bhh,
                                   const float* __restrict__ Wd, const float* __restrict__ bd,
                                   _Float16* __restrict__ WcH, float* __restrict__ bc) {
  const int t = blockIdx.x;   // gate row 0..511
  const int l = threadIdx.x;  // latent col 0..127
  float s = Whh[t * Ln + l];
#pragma unroll
  for (int j = 0; j < Fn; ++j) s += Wih[t * Fn + j] * Wd[j * Ln + l];
  WcH[t * Ln + l] = (_Float16)s;
  if (l == 0) {
    float sb = bih[t] + bhh[t];
#pragma unroll
    for (int j = 0; j < Fn; ++j) sb += Wih[t * Fn + j] * bd[j];
    bc[t] = sb;
  }
}

// Persistent RNN: 256 blocks x 512 threads, 2 batch elems per block.
// fp16 weights packed as half2 in VGPRs (96 regs) + fp32 accumulate via
// v_dot2_f32_f16 -> working set fits the 128-VGPR budget the backend insists
// on (r2-r4: asking for more always ended in AGPR copies or scratch spill).
// h and x live in LDS as fp16 (halved LDS traffic).
// Thread t: q = t&3 (K-quarter), rA = t>>2 (latent). Owns gate rows
// {rA, rA+128, rA+256, rA+384} = (i,f,g,o) of latent rA -> after the 4-lane
// DPP quad reduce the cell update is LOCAL; one barrier per step.
// r5 bug fixed here: x staging is 32 feature-PAIRS per elem (f2 = t&31,
// e_ = t>>5, active t<64) -- r5 used t&63 which read past the end of x and
// wrote past the end of xs[] in LDS (GPU memory fault -> core dump).
__global__ __launch_bounds__(512, 1) __attribute__((amdgpu_waves_per_eu(2, 2)))
void rae_persistent_kernel(
    const float* __restrict__ x,
    const _Float16* __restrict__ WhE, const _Float16* __restrict__ WxE,
    const float* __restrict__ bih_e, const float* __restrict__ bhh_e,
    const _Float16* __restrict__ WcH, const float* __restrict__ bc,
    const _Float16* __restrict__ WdH, const float* __restrict__ bd,
    float* __restrict__ out) {
  const int t = threadIdx.x;
  const int q = t & 3;    // K-quarter: h[32q..32q+32), x[16q..16q+16)
  const int rA = t >> 2;  // latent 0..127
  const int b0 = blockIdx.x * 2;

  __shared__ __align__(16) _Float16 hs[2][2][Ln];  // [buf][elem][latent]
  __shared__ __align__(16) _Float16 xs[2][2][Fn];  // [buf][elem][feature]

  // ---- encoder weights: 4 rows x (16 h-half2 + 8 x-half2) = 96 u32 regs ----
  u32 wh[4][16], wx[4][8];
  float bias[4];
#pragma unroll
  for (int g = 0; g < 4; ++g) {
    const int row = g * Ln + rA;
    const uint4* ph = (const uint4*)(WhE + row * Ln + q * 32);
#pragma unroll
    for (int k = 0; k < 4; ++k) {
      uint4 v = ph[k];
      wh[g][4 * k] = v.x; wh[g][4 * k + 1] = v.y; wh[g][4 * k + 2] = v.z; wh[g][4 * k + 3] = v.w;
    }
    const uint4* px = (const uint4*)(WxE + row * Fn + q * 16);
#pragma unroll
    for (int k = 0; k < 2; ++k) {
      uint4 v = px[k];
      wx[g][4 * k] = v.x; wx[g][4 * k + 1] = v.y; wx[g][4 * k + 2] = v.z; wx[g][4 * k + 3] = v.w;
    }
    bias[g] = bih_e[row] + bhh_e[row];
  }

  float c = 0.0f;  // lanes q<2: cell state for (latent rA, elem q)

  // x staging slot: t<64 -> elem e_ = t>>5, feature pair f2 = t&31 (2 floats each)
  const int f2 = t & 31, e_ = (t >> 5) & 1;
  const float* xbase = x + (size_t)(b0 + e_) * Sn * Fn + 2 * f2;

  if (t < 128) ((u32*)&hs[0][0][0])[t] = 0u;  // zero both elems of h buffer 0
  if (t < 64) {
    float2 v = *(const float2*)xbase;
    h2 p = {(_Float16)v.x, (_Float16)v.y};
    ((u32*)&xs[0][e_][0])[f2] = __builtin_bit_cast(u32, p);
  }
  __syncthreads();

  // ================= encoder: 1024 steps =================
  for (int step = 0; step < Sn; ++step) {
    const int cur = step & 1, nx = cur ^ 1;
    float2 xv;
    const bool pf = (t < 64) && (step + 1 < Sn);
    if (pf) xv = *(const float2*)(xbase + (size_t)(step + 1) * Fn);

    float a[4][2];
#pragma unroll
    for (int g = 0; g < 4; ++g) { a[g][0] = 0.0f; a[g][1] = 0.0f; }

    const uint4* h0p = (const uint4*)&hs[cur][0][q * 32];
    const uint4* h1p = (const uint4*)&hs[cur][1][q * 32];
#pragma unroll
    for (int k = 0; k < 4; ++k) {
      uint4 v0 = h0p[k], v1 = h1p[k];
#pragma unroll
      for (int g = 0; g < 4; ++g) {
        a[g][0] = fdot2(wh[g][4 * k], v0.x, a[g][0]);
        a[g][0] = fdot2(wh[g][4 * k + 1], v0.y, a[g][0]);
        a[g][0] = fdot2(wh[g][4 * k + 2], v0.z, a[g][0]);
        a[g][0] = fdot2(wh[g][4 * k + 3], v0.w, a[g][0]);
        a[g][1] = fdot2(wh[g][4 * k], v1.x, a[g][1]);
        a[g][1] = fdot2(wh[g][4 * k + 1], v1.y, a[g][1]);
        a[g][1] = fdot2(wh[g][4 * k + 2], v1.z, a[g][1]);
        a[g][1] = fdot2(wh[g][4 * k + 3], v1.w, a[g][1]);
      }
    }
    const uint4* x0p = (const uint4*)&xs[cur][0][q * 16];
    const uint4* x1p = (const uint4*)&xs[cur][1][q * 16];
#pragma unroll
    for (int k = 0; k < 2; ++k) {
      uint4 v0 = x0p[k], v1 = x1p[k];
#pragma unroll
      for (int g = 0; g < 4; ++g) {
        a[g][0] = fdot2(wx[g][4 * k], v0.x, a[g][0]);
        a[g][0] = fdot2(wx[g][4 * k + 1], v0.y, a[g][0]);
        a[g][0] = fdot2(wx[g][4 * k + 2], v0.z, a[g][0]);
        a[g][0] = fdot2(wx[g][4 * k + 3], v0.w, a[g][0]);
        a[g][1] = fdot2(wx[g][4 * k], v1.x, a[g][1]);
        a[g][1] = fdot2(wx[g][4 * k + 1], v1.y, a[g][1]);
        a[g][1] = fdot2(wx[g][4 * k + 2], v1.z, a[g][1]);
        a[g][1] = fdot2(wx[g][4 * k + 3], v1.w, a[g][1]);
      }
    }
    // quad all-reduce (DPP xor1, xor2)
#pragma unroll
    for (int g = 0; g < 4; ++g) {
      a[g][0] = dpp_add<0x4E>(dpp_add<0xB1>(a[g][0]));
      a[g][1] = dpp_add<0x4E>(dpp_add<0xB1>(a[g][1]));
    }
    if (q < 2) {  // lane q handles elem q: local cell update
      float gi = fsig(a[0][q] + bias[0]);
      float gf = fsig(a[1][q] + bias[1]);
      float gg = ftanh(a[2][q] + bias[2]);
      float go = fsig(a[3][q] + bias[3]);
      c = gf * c + gi * gg;
      hs[nx][q][rA] = (_Float16)(go * ftanh(c));
    }
    if (pf) {
      h2 p = {(_Float16)xv.x, (_Float16)xv.y};
      ((u32*)&xs[nx][e_][0])[f2] = __builtin_bit_cast(u32, p);
    }
    __syncthreads();
  }

  // ================= decoder: 1024 steps =================
#pragma unroll
  for (int g = 0; g < 4; ++g) {  // reload wh with folded W_comb (fp16)
    const int row = g * Ln + rA;
    const uint4* pc = (const uint4*)(WcH + row * Ln + q * 32);
#pragma unroll
    for (int k = 0; k < 4; ++k) {
      uint4 v = pc[k];
      wh[g][4 * k] = v.x; wh[g][4 * k + 1] = v.y; wh[g][4 * k + 2] = v.z; wh[g][4 * k + 3] = v.w;
    }
    bias[g] = bc[row];
  }
  // dense epilogue: quad (4 lanes) covers the K-quarters of one (oj, eo)
  const int oj = (t >> 2) & 63, eo = t >> 8;
  u32 dw[16];
  {
    const uint4* pd = (const uint4*)(WdH + oj * Ln + q * 32);
#pragma unroll
    for (int k = 0; k < 4; ++k) {
      uint4 v = pd[k];
      dw[4 * k] = v.x; dw[4 * k + 1] = v.y; dw[4 * k + 2] = v.z; dw[4 * k + 3] = v.w;
    }
  }
  const float dbias = bd[oj];
  float* op = out + (size_t)(b0 + eo) * Sn * Fn + (size_t)(Sn - 1) * Fn + oj;

  for (int step = 0; step < Sn; ++step) {
    const int cur = step & 1, nx = cur ^ 1;
    float a[4][2];
#pragma unroll
    for (int g = 0; g < 4; ++g) { a[g][0] = 0.0f; a[g][1] = 0.0f; }

    const uint4* h0p = (const uint4*)&hs[cur][0][q * 32];
    const uint4* h1p = (const uint4*)&hs[cur][1][q * 32];
#pragma unroll
    for (int k = 0; k < 4; ++k) {
      uint4 v0 = h0p[k], v1 = h1p[k];
#pragma unroll
      for (int g = 0; g < 4; ++g) {
        a[g][0] = fdot2(wh[g][4 * k], v0.x, a[g][0]);
        a[g][0] = fdot2(wh[g][4 * k + 1], v0.y, a[g][0]);
        a[g][0] = fdot2(wh[g][4 * k + 2], v0.z, a[g][0]);
        a[g][0] = fdot2(wh[g][4 * k + 3], v0.w, a[g][0]);
        a[g][1] = fdot2(wh[g][4 * k], v1.x, a[g][1]);
        a[g][1] = fdot2(wh[g][4 * k + 1], v1.y, a[g][1]);
        a[g][1] = fdot2(wh[g][4 * k + 2], v1.z, a[g][1]);
        a[g][1] = fdot2(wh[g][4 * k + 3], v1.w, a[g][1]);
      }
    }
#pragma unroll
    for (int g = 0; g < 4; ++g) {
      a[g][0] = dpp_add<0x4E>(dpp_add<0xB1>(a[g][0]));
      a[g][1] = dpp_add<0x4E>(dpp_add<0xB1>(a[g][1]));
    }
    if (q < 2) {
      float gi = fsig(a[0][q] + bias[0]);
      float gf = fsig(a[1][q] + bias[1]);
      float gg = ftanh(a[2][q] + bias[2]);
      float go = fsig(a[3][q] + bias[3]);
      c = gf * c + gi * gg;
      hs[nx][q][rA] = (_Float16)(go * ftanh(c));
    }
    __syncthreads();

    // dense epilogue on just-written h (buffer nx): out[b0+eo, S-1-step, oj]
    const uint4* he = (const uint4*)&hs[nx][eo][q * 32];
    float d = 0.0f;
#pragma unroll
    for (int k = 0; k < 4; ++k) {
      uint4 v = he[k];
      d = fdot2(dw[4 * k], v.x, d);
      d = fdot2(dw[4 * k + 1], v.y, d);
      d = fdot2(dw[4 * k + 2], v.z, d);
      d = fdot2(dw[4 * k + 3], v.w, d);
    }
    d = dpp_add<0x4E>(dpp_add<0xB1>(d));
    if (q == 0) op[0] = d + dbias;
    op -= Fn;
  }
}

extern "C" void kernel_launch(void* const* d_in, const int* in_sizes, int n_in,
                              void* d_out, int out_size, void* d_ws, size_t ws_size,
                              hipStream_t stream) {
  const float* x     = (const float*)d_in[0];
  const float* Wih_e = (const float*)d_in[1];
  const float* Whh_e = (const float*)d_in[2];
  const float* bih_e = (const float*)d_in[3];
  const float* bhh_e = (const float*)d_in[4];
  const float* Wih_d = (const float*)d_in[5];
  const float* Whh_d = (const float*)d_in[6];
  const float* bih_d = (const float*)d_in[7];
  const float* bhh_d = (const float*)d_in[8];
  const float* Wd    = (const float*)d_in[9];
  const float* bd    = (const float*)d_in[10];
  float* out = (float*)d_out;

  // workspace layout (fp16 weight copies + fp32 combined bias)
  _Float16* WhE = (_Float16*)d_ws;           // 512*128
  _Float16* WxE = WhE + Gn * Ln;             // 512*64
  _Float16* WcH = WxE + Gn * Fn;             // 512*128
  _Float16* WdH = WcH + Gn * Ln;             // 64*128
  float* bc = (float*)(WdH + Fn * Ln);       // 512

  pack_kernel<<<256, 256, 0, stream>>>(Wih_e, Whh_e, Wd, WhE, WxE, WdH);
  combine_dec_kernel<<<Gn, Ln, 0, stream>>>(Wih_d, Whh_d, bih_d, bhh_d, Wd, bd, WcH, bc);
  rae_persistent_kernel<<<Bn / 2, 512, 0, stream>>>(x, WhE, WxE, bih_e, bhh_e,
                                                    WcH, bc, WdH, bd, out);
}